// Round 3
// baseline (1954.908 us; speedup 1.0000x reference)
//
#include <hip/hip_runtime.h>
#include <hip/hip_bf16.h>

typedef __hip_bfloat16 bf16;
typedef __attribute__((ext_vector_type(8))) short short8;
typedef __attribute__((ext_vector_type(4))) float f32x4;

#define NN 20000
#define NE 80000
#define DD 128
#define NITER 15

__device__ inline short f2bs(float f) {
  bf16 h = (bf16)f;
  return *(reinterpret_cast<short*>(&h));
}

// ---------------------------------------------------------------------------
// dtype auto-detect: even uint16 halfwords of a bf16 array have sane exponents
// (~100%); of an fp32 array they are low mantissa bits (random, ~36% sane).
// flag = 1 -> inputs/outputs are bf16 ; flag = 0 -> fp32.
// ---------------------------------------------------------------------------
__global__ void detect_kernel(const unsigned short* __restrict__ p, int nhalf,
                              int* __restrict__ flag) {
  __shared__ int cs[256], ct[256];
  const int t = threadIdx.x;
  int sane = 0, tot = 0;
  for (int i = 2 * t; i < nhalf; i += 512) {
    unsigned short v = p[i];
    int e = (v >> 7) & 0xFF;
    tot++;
    if (v == 0 || (e >= 80 && e <= 170)) sane++;
  }
  cs[t] = sane; ct[t] = tot;
  __syncthreads();
  for (int o = 128; o > 0; o >>= 1) {
    if (t < o) { cs[t] += cs[t + o]; ct[t] += ct[t + o]; }
    __syncthreads();
  }
  if (t == 0) *flag = (cs[0] * 10 > ct[0] * 7) ? 1 : 0;
}

// src (bf16 or fp32 per flag) -> fp32
__global__ void in2f_kernel(const void* __restrict__ src, float* __restrict__ dst,
                            int n, const int* __restrict__ flag) {
  int i = blockIdx.x * 256 + threadIdx.x;
  if (i < n) {
    dst[i] = (*flag) ? (float)((const bf16*)src)[i] : ((const float*)src)[i];
  }
}

// W [NITER][K][128] (bf16 or fp32) -> Wt [NITER][128][K] bf16
__global__ void w2t_kernel(const void* __restrict__ W, bf16* __restrict__ Wt,
                           int K, const int* __restrict__ flag) {
  int i = blockIdx.x * 256 + threadIdx.x;
  int total = NITER * K * DD;
  if (i < total) {
    float v = (*flag) ? (float)((const bf16*)W)[i] : ((const float*)W)[i];
    int t = i / (K * DD);
    int rem = i - t * K * DD;
    int k = rem >> 7;          // DD == 128
    int n = rem & 127;
    Wt[(size_t)t * K * DD + (size_t)n * K + k] = (bf16)v;
  }
}

// fp32 states -> d_out in detected dtype
__global__ void outw_kernel(const float* __restrict__ xf, const float* __restrict__ ef,
                            void* __restrict__ out, const int* __restrict__ flag) {
  int i = blockIdx.x * 256 + threadIdx.x;
  const int nx = NN * DD, total = (NN + NE) * DD;
  if (i < total) {
    float v = (i < nx) ? xf[i] : ef[i - nx];
    if (*flag) ((bf16*)out)[i] = (bf16)v;
    else       ((float*)out)[i] = v;
  }
}

// ---------------------------------------------------------------------------
// Fused MLP GEMM: C[M x 128] = act(A[M x K] @ W[K x 128] + bias), optional
// LayerNorm+residual epilogue (residual state fp32). Tile 128x128, 4 waves,
// 16x16x32 bf16 MFMA, register-staged LDS.
// AMODE 0: A given directly as bf16 [M][K] (in-place safe: own rows only)
// AMODE 1: edge gather  A = concat(xf[row[m]], xf[col[m]], ef[m])  (K=384)
// AMODE 2: node gather  A = concat(xf[m], aggf[m])                 (K=256)
// ---------------------------------------------------------------------------
template<int K, int AMODE, bool RELU, bool LN>
__global__ __launch_bounds__(256) void mlp_gemm(
    const bf16*  __restrict__ A,
    const float* __restrict__ S0,
    const float* __restrict__ S1,
    const int*   __restrict__ eidx,
    const bf16*  __restrict__ Wt,     // [128][K]
    const float* __restrict__ bias,   // [128] fp32
    bf16*        __restrict__ Hout,   // !LN
    const float* __restrict__ gamma,  // LN
    const float* __restrict__ beta,   // LN
    float*       __restrict__ stf,    // LN: fp32 residual state (in/out)
    int M)
{
  __shared__ __align__(16) bf16 Als[128 * 32];
  __shared__ __align__(16) bf16 Bls[128 * 32];
  __shared__ float redS[2][128];
  __shared__ float redQ[2][128];
  __shared__ float mrow[128][2];

  const int tid  = threadIdx.x;
  const int lane = tid & 63;
  const int wv   = tid >> 6;
  const int wm   = wv >> 1, wn = wv & 1;
  const int l15  = lane & 15, quad = lane >> 4;
  const int m0   = blockIdx.x * 128;

  const int rl0 = tid >> 2;          // 0..63: staging row slot
  const int ks8 = (tid & 3) * 8;     // 8-elem chunk within 32-wide K slab

  const int cr0 = min(m0 + rl0,      M - 1);
  const int cr1 = min(m0 + rl0 + 64, M - 1);
  int ir0 = 0, ic0 = 0, ir1 = 0, ic1 = 0;
  if (AMODE == 1) {
    ir0 = eidx[cr0];      ic0 = eidx[NE + cr0];
    ir1 = eidx[cr1];      ic1 = eidx[NE + cr1];
  }

  f32x4 acc[4][4];
#pragma unroll
  for (int i = 0; i < 4; i++)
#pragma unroll
    for (int j = 0; j < 4; j++) acc[i][j] = (f32x4){0.f, 0.f, 0.f, 0.f};

  const int nsteps = K / 32;
  for (int s = 0; s < nsteps; s++) {
    const int kk = s * 32;
    // ---- global -> registers ----
    short8 b0 = *(const short8*)(Wt + (size_t)rl0 * K + kk + ks8);
    short8 b1 = *(const short8*)(Wt + (size_t)(rl0 + 64) * K + kk + ks8);
    short8 a0, a1;
    if (AMODE == 0) {
      a0 = *(const short8*)(A + (size_t)cr0 * K + kk + ks8);
      a1 = *(const short8*)(A + (size_t)cr1 * K + kk + ks8);
    } else {
      const float *p0, *p1;
      const int ks = (kk & 127) + ks8;
      if (AMODE == 1) {
        const int seg = kk >> 7;
        if (seg == 0)      { p0 = S0 + (size_t)ir0 * DD + ks; p1 = S0 + (size_t)ir1 * DD + ks; }
        else if (seg == 1) { p0 = S0 + (size_t)ic0 * DD + ks; p1 = S0 + (size_t)ic1 * DD + ks; }
        else               { p0 = S1 + (size_t)cr0 * DD + ks; p1 = S1 + (size_t)cr1 * DD + ks; }
      } else {
        const float* src = (kk >> 7) ? S1 : S0;
        p0 = src + (size_t)cr0 * DD + ks;
        p1 = src + (size_t)cr1 * DD + ks;
      }
      f32x4 u0 = *(const f32x4*)p0, u1 = *(const f32x4*)(p0 + 4);
      f32x4 v0 = *(const f32x4*)p1, v1 = *(const f32x4*)(p1 + 4);
#pragma unroll
      for (int j = 0; j < 4; j++) {
        a0[j]     = f2bs(u0[j]);
        a0[j + 4] = f2bs(u1[j]);
        a1[j]     = f2bs(v0[j]);
        a1[j + 4] = f2bs(v1[j]);
      }
    }
    // ---- registers -> LDS ----
    __syncthreads();   // prior iteration's fragment reads complete
    *(short8*)&Als[rl0 * 32 + ks8]        = a0;
    *(short8*)&Als[(rl0 + 64) * 32 + ks8] = a1;
    *(short8*)&Bls[rl0 * 32 + ks8]        = b0;
    *(short8*)&Bls[(rl0 + 64) * 32 + ks8] = b1;
    __syncthreads();

    // ---- LDS -> fragments -> MFMA ----
    short8 af[4], bfr[4];
#pragma unroll
    for (int mi = 0; mi < 4; mi++)
      af[mi] = *(const short8*)&Als[(wm * 64 + mi * 16 + l15) * 32 + quad * 8];
#pragma unroll
    for (int ni = 0; ni < 4; ni++)
      bfr[ni] = *(const short8*)&Bls[(wn * 64 + ni * 16 + l15) * 32 + quad * 8];
#pragma unroll
    for (int mi = 0; mi < 4; mi++)
#pragma unroll
      for (int ni = 0; ni < 4; ni++)
        acc[mi][ni] = __builtin_amdgcn_mfma_f32_16x16x32_bf16(af[mi], bfr[ni], acc[mi][ni], 0, 0, 0);
  }

  float bv[4], gv[4], btv[4];
#pragma unroll
  for (int ni = 0; ni < 4; ni++) {
    const int col = wn * 64 + ni * 16 + l15;
    bv[ni] = bias[col];
    if (LN) { gv[ni] = gamma[col]; btv[ni] = beta[col]; }
  }

  if (!LN) {
#pragma unroll
    for (int mi = 0; mi < 4; mi++)
#pragma unroll
      for (int r = 0; r < 4; r++) {
        const int m = m0 + wm * 64 + mi * 16 + quad * 4 + r;
        if (m < M) {
#pragma unroll
          for (int ni = 0; ni < 4; ni++) {
            const int col = wn * 64 + ni * 16 + l15;
            float v = acc[mi][ni][r] + bv[ni];
            if (RELU) v = fmaxf(v, 0.f);
            Hout[(size_t)m * DD + col] = (bf16)v;
          }
        }
      }
  } else {
    float s1v[4][4], s2v[4][4];
#pragma unroll
    for (int mi = 0; mi < 4; mi++)
#pragma unroll
      for (int r = 0; r < 4; r++) {
        float a = 0.f, b = 0.f;
#pragma unroll
        for (int ni = 0; ni < 4; ni++) {
          const float v = acc[mi][ni][r] + bv[ni];
          a += v; b += v * v;
        }
        s1v[mi][r] = a; s2v[mi][r] = b;
      }
#pragma unroll
    for (int off = 1; off < 16; off <<= 1) {
#pragma unroll
      for (int mi = 0; mi < 4; mi++)
#pragma unroll
        for (int r = 0; r < 4; r++) {
          s1v[mi][r] += __shfl_xor(s1v[mi][r], off);
          s2v[mi][r] += __shfl_xor(s2v[mi][r], off);
        }
    }
    if (l15 == 0) {
#pragma unroll
      for (int mi = 0; mi < 4; mi++)
#pragma unroll
        for (int r = 0; r < 4; r++) {
          const int rl = wm * 64 + mi * 16 + quad * 4 + r;
          redS[wn][rl] = s1v[mi][r];
          redQ[wn][rl] = s2v[mi][r];
        }
    }
    __syncthreads();
    if (tid < 128) {
      const float t1 = redS[0][tid] + redS[1][tid];
      const float t2 = redQ[0][tid] + redQ[1][tid];
      const float mu = t1 * (1.0f / 128.0f);
      const float var = fmaxf(t2 * (1.0f / 128.0f) - mu * mu, 0.0f);
      mrow[tid][0] = mu;
      mrow[tid][1] = rsqrtf(var + 1e-5f);
    }
    __syncthreads();
#pragma unroll
    for (int mi = 0; mi < 4; mi++)
#pragma unroll
      for (int r = 0; r < 4; r++) {
        const int rl = wm * 64 + mi * 16 + quad * 4 + r;
        const int m = m0 + rl;
        if (m < M) {
          const float mu = mrow[rl][0], rs = mrow[rl][1];
#pragma unroll
          for (int ni = 0; ni < 4; ni++) {
            const int col = wn * 64 + ni * 16 + l15;
            const float v = acc[mi][ni][r] + bv[ni];
            const float lnv = (v - mu) * rs * gv[ni] + btv[ni];
            const size_t idx = (size_t)m * DD + col;
            stf[idx] = lnv + stf[idx];
          }
        }
      }
  }
}

// --------------------------- CSR build + aggregate -------------------------
__global__ void zero_kernel(int* __restrict__ p, int n) {
  int i = blockIdx.x * 256 + threadIdx.x;
  if (i < n) p[i] = 0;
}

__global__ void hist_kernel(const int* __restrict__ eidx, int* __restrict__ counts) {
  int e = blockIdx.x * 256 + threadIdx.x;
  if (e < NE) atomicAdd(&counts[eidx[NE + e]], 1);
}

__global__ void scan_kernel(const int* __restrict__ counts, int* __restrict__ offs,
                            int* __restrict__ cursor) {
  __shared__ int sums[1024];
  const int t = threadIdx.x;
  const int base = t * 20;
  int local[20];
  int s = 0;
  for (int i = 0; i < 20; i++) {
    int idx = base + i;
    int c = (idx < NN) ? counts[idx] : 0;
    local[i] = s; s += c;
  }
  sums[t] = s;
  __syncthreads();
  for (int off = 1; off < 1024; off <<= 1) {
    int v = 0;
    if (t >= off) v = sums[t - off];
    __syncthreads();
    if (t >= off) sums[t] += v;
    __syncthreads();
  }
  int excl = (t == 0) ? 0 : sums[t - 1];
  for (int i = 0; i < 20; i++) {
    int idx = base + i;
    if (idx < NN) { offs[idx] = excl + local[i]; cursor[idx] = 0; }
  }
  if (t == 1023) offs[NN] = sums[1023];
}

__global__ void fill_kernel(const int* __restrict__ eidx, const int* __restrict__ offs,
                            int* __restrict__ cursor, int* __restrict__ sorted) {
  int e = blockIdx.x * 256 + threadIdx.x;
  if (e < NE) {
    int n = eidx[NE + e];
    int p = atomicAdd(&cursor[n], 1);
    sorted[offs[n] + p] = e;
  }
}

__global__ void aggregate_kernel(const float* __restrict__ ef, const int* __restrict__ offs,
                                 const int* __restrict__ sorted, float* __restrict__ aggf) {
  const int node = blockIdx.x * 4 + (threadIdx.x >> 6);
  const int lane = threadIdx.x & 63;
  if (node >= NN) return;
  const int s = offs[node], t = offs[node + 1];
  float a0 = 0.f, a1 = 0.f;
  for (int i = s; i < t; i++) {
    const int e = sorted[i];
    a0 += ef[(size_t)e * DD + lane];
    a1 += ef[(size_t)e * DD + 64 + lane];
  }
  aggf[(size_t)node * DD + lane]      = a0;
  aggf[(size_t)node * DD + 64 + lane] = a1;
}

// ---------------------------------------------------------------------------
extern "C" void kernel_launch(void* const* d_in, const int* in_sizes, int n_in,
                              void* d_out, int out_size, void* d_ws, size_t ws_size,
                              hipStream_t stream) {
  const void* x_in = d_in[0];
  const void* e_in = d_in[1];
  const void* eW0 = d_in[2];
  const void* eB0 = d_in[3];
  const void* eW1 = d_in[4];
  const void* eB1 = d_in[5];
  const void* eW2 = d_in[6];
  const void* eB2 = d_in[7];
  const void* eG  = d_in[8];
  const void* eBt = d_in[9];
  const void* nW0 = d_in[10];
  const void* nB0 = d_in[11];
  const void* nW1 = d_in[12];
  const void* nB1 = d_in[13];
  const void* nW2 = d_in[14];
  const void* nB2 = d_in[15];
  const void* nG  = d_in[16];
  const void* nBt = d_in[17];
  const int*  eidx = (const int*)d_in[18];

  char* ws = (char*)d_ws;
  size_t off = 0;
  auto alloc = [&](size_t bytes) -> char* {
    char* p = ws + off;
    off = (off + bytes + 255) & ~(size_t)255;
    return p;
  };

  float* xf   = (float*)alloc((size_t)NN * DD * 4);   // node state fp32
  float* ef   = (float*)alloc((size_t)NE * DD * 4);   // edge state fp32
  float* aggf = (float*)alloc((size_t)NN * DD * 4);   // scatter-sum result
  bf16*  H0   = (bf16*)alloc((size_t)NE * DD * 2);    // hidden (in-place reuse)
  bf16*  eW0t = (bf16*)alloc((size_t)NITER * 384 * DD * 2);
  bf16*  eW1t = (bf16*)alloc((size_t)NITER * 128 * DD * 2);
  bf16*  eW2t = (bf16*)alloc((size_t)NITER * 128 * DD * 2);
  bf16*  nW0t = (bf16*)alloc((size_t)NITER * 256 * DD * 2);
  bf16*  nW1t = (bf16*)alloc((size_t)NITER * 128 * DD * 2);
  bf16*  nW2t = (bf16*)alloc((size_t)NITER * 128 * DD * 2);
  const int NB = NITER * DD;
  float* eB0f = (float*)alloc(NB * 4);
  float* eB1f = (float*)alloc(NB * 4);
  float* eB2f = (float*)alloc(NB * 4);
  float* eGf  = (float*)alloc(NB * 4);
  float* eBtf = (float*)alloc(NB * 4);
  float* nB0f = (float*)alloc(NB * 4);
  float* nB1f = (float*)alloc(NB * 4);
  float* nB2f = (float*)alloc(NB * 4);
  float* nGf  = (float*)alloc(NB * 4);
  float* nBtf = (float*)alloc(NB * 4);
  int* counts = (int*)alloc((size_t)NN * 4);
  int* cursor = (int*)alloc((size_t)NN * 4);
  int* offs   = (int*)alloc((size_t)(NN + 1) * 4);
  int* sorted = (int*)alloc((size_t)NE * 4);
  int* flag   = (int*)alloc(4);

  // dtype detection on x (sample 256K halfwords; safe under both dtypes)
  detect_kernel<<<1, 256, 0, stream>>>((const unsigned short*)x_in, 262144, flag);

  // canonicalize inputs
  in2f_kernel<<<(NN * DD + 255) / 256, 256, 0, stream>>>(x_in, xf, NN * DD, flag);
  in2f_kernel<<<(NE * DD + 255) / 256, 256, 0, stream>>>(e_in, ef, NE * DD, flag);
  w2t_kernel<<<(NITER * 384 * DD + 255) / 256, 256, 0, stream>>>(eW0, eW0t, 384, flag);
  w2t_kernel<<<(NITER * 128 * DD + 255) / 256, 256, 0, stream>>>(eW1, eW1t, 128, flag);
  w2t_kernel<<<(NITER * 128 * DD + 255) / 256, 256, 0, stream>>>(eW2, eW2t, 128, flag);
  w2t_kernel<<<(NITER * 256 * DD + 255) / 256, 256, 0, stream>>>(nW0, nW0t, 256, flag);
  w2t_kernel<<<(NITER * 128 * DD + 255) / 256, 256, 0, stream>>>(nW1, nW1t, 128, flag);
  w2t_kernel<<<(NITER * 128 * DD + 255) / 256, 256, 0, stream>>>(nW2, nW2t, 128, flag);
  in2f_kernel<<<(NB + 255) / 256, 256, 0, stream>>>(eB0, eB0f, NB, flag);
  in2f_kernel<<<(NB + 255) / 256, 256, 0, stream>>>(eB1, eB1f, NB, flag);
  in2f_kernel<<<(NB + 255) / 256, 256, 0, stream>>>(eB2, eB2f, NB, flag);
  in2f_kernel<<<(NB + 255) / 256, 256, 0, stream>>>(eG,  eGf,  NB, flag);
  in2f_kernel<<<(NB + 255) / 256, 256, 0, stream>>>(eBt, eBtf, NB, flag);
  in2f_kernel<<<(NB + 255) / 256, 256, 0, stream>>>(nB0, nB0f, NB, flag);
  in2f_kernel<<<(NB + 255) / 256, 256, 0, stream>>>(nB1, nB1f, NB, flag);
  in2f_kernel<<<(NB + 255) / 256, 256, 0, stream>>>(nB2, nB2f, NB, flag);
  in2f_kernel<<<(NB + 255) / 256, 256, 0, stream>>>(nG,  nGf,  NB, flag);
  in2f_kernel<<<(NB + 255) / 256, 256, 0, stream>>>(nBt, nBtf, NB, flag);

  // CSR for segment_sum over destination nodes
  zero_kernel<<<(NN + 255) / 256, 256, 0, stream>>>(counts, NN);
  hist_kernel<<<(NE + 255) / 256, 256, 0, stream>>>(eidx, counts);
  scan_kernel<<<1, 1024, 0, stream>>>(counts, offs, cursor);
  fill_kernel<<<(NE + 255) / 256, 256, 0, stream>>>(eidx, offs, cursor, sorted);

  const int egrid = NE / 128;               // 625
  const int ngrid = (NN + 127) / 128;       // 157

  for (int t = 0; t < NITER; t++) {
    mlp_gemm<384, 1, true, false><<<egrid, 256, 0, stream>>>(
        nullptr, xf, ef, eidx, eW0t + (size_t)t * 384 * DD, eB0f + t * DD,
        H0, nullptr, nullptr, nullptr, NE);
    mlp_gemm<128, 0, true, false><<<egrid, 256, 0, stream>>>(
        H0, nullptr, nullptr, nullptr, eW1t + (size_t)t * 128 * DD, eB1f + t * DD,
        H0, nullptr, nullptr, nullptr, NE);
    mlp_gemm<128, 0, false, true><<<egrid, 256, 0, stream>>>(
        H0, nullptr, nullptr, nullptr, eW2t + (size_t)t * 128 * DD, eB2f + t * DD,
        nullptr, eGf + t * DD, eBtf + t * DD, ef, NE);
    aggregate_kernel<<<(NN + 3) / 4, 256, 0, stream>>>(ef, offs, sorted, aggf);
    mlp_gemm<256, 2, true, false><<<ngrid, 256, 0, stream>>>(
        nullptr, xf, aggf, nullptr, nW0t + (size_t)t * 256 * DD, nB0f + t * DD,
        H0, nullptr, nullptr, nullptr, NN);
    mlp_gemm<128, 0, true, false><<<ngrid, 256, 0, stream>>>(
        H0, nullptr, nullptr, nullptr, nW1t + (size_t)t * 128 * DD, nB1f + t * DD,
        H0, nullptr, nullptr, nullptr, NN);
    mlp_gemm<128, 0, false, true><<<ngrid, 256, 0, stream>>>(
        H0, nullptr, nullptr, nullptr, nW2t + (size_t)t * 128 * DD, nB2f + t * DD,
        nullptr, nGf + t * DD, nBtf + t * DD, xf, NN);
  }

  outw_kernel<<<((NN + NE) * DD + 255) / 256, 256, 0, stream>>>(xf, ef, d_out, flag);
}